// Round 1
// baseline (367.179 us; speedup 1.0000x reference)
//
#include <hip/hip_runtime.h>

#define DD 256   // in_dim
#define HH 128   // per-branch out dim (2H = 256 = DD)
#define CC 64    // n_class
#define BB 1024
#define SS1 25
#define SS2 10

// ---------------------------------------------------------------------------
// K1: row-mean with optional index gather.
//   GATHER=true : out[i][:] = 1/F * sum_j features[ids[i*F+j]][:]
//   GATHER=false: out[i][:] = 1/F * sum_j src[(i*F+j)][:]
// one 64-lane wave per output row; lane handles 4 consecutive floats (float4)
// ---------------------------------------------------------------------------
template <bool GATHER>
__global__ void mean_gather(const float* __restrict__ src,
                            const int* __restrict__ ids,
                            float* __restrict__ out, int F, float inv) {
    const int row  = blockIdx.x;
    const int lane = threadIdx.x;            // 0..63
    const int base = row * F;
    float4 acc = {0.f, 0.f, 0.f, 0.f};
    for (int j = 0; j < F; ++j) {
        long srow = GATHER ? (long)ids[base + j] : (long)(base + j);
        float4 v = ((const float4*)(src + srow * DD))[lane];
        acc.x += v.x; acc.y += v.y; acc.z += v.z; acc.w += v.w;
    }
    acc.x *= inv; acc.y *= inv; acc.z *= inv; acc.w *= inv;
    ((float4*)(out + (long)row * DD))[lane] = acc;
}

// ---------------------------------------------------------------------------
// K2: fused aggregator layer:
//   out[i][0:128]   = act( X[i]   . Wx + bx )   with X[i] = features[idsX[i]] if GATHER
//   out[i][128:256] = act( Nbr[i] . Wn + bn )
// block = 256 threads = 256 output columns; RT=16 rows per block.
// A-tiles in LDS; inner-loop LDS read is wave-uniform => broadcast (free).
// W reads per k are coalesced across the wave and L1/L2 resident (128 KB).
// ---------------------------------------------------------------------------
template <bool RELU, bool GATHER>
__global__ __launch_bounds__(256)
void agg_layer(const float* __restrict__ Xsrc, const int* __restrict__ idsX,
               const float* __restrict__ Nbr,
               const float* __restrict__ Wx, const float* __restrict__ bx,
               const float* __restrict__ Wn, const float* __restrict__ bn,
               float* __restrict__ out) {
    constexpr int RT = 16;
    __shared__ float aX[RT][DD];   // 16 KB
    __shared__ float aN[RT][DD];   // 16 KB
    const int r0 = blockIdx.x * RT;
    const int t  = threadIdx.x;

    // stage: RT*256*2 floats; each thread does 8 float4 loads (4 X + 4 N)
    for (int basei = 0; basei < RT * DD; basei += 1024) {
        int idx = basei + t * 4;
        int r = idx >> 8, k = idx & 255;
        long row  = r0 + r;
        long xrow = GATHER ? (long)idsX[row] : row;
        *(float4*)&aX[r][k] = *(const float4*)(Xsrc + xrow * DD + k);
        *(float4*)&aN[r][k] = *(const float4*)(Nbr + row * DD + k);
    }
    __syncthreads();

    const bool xhalf = (t < HH);                 // wave-uniform (waves 0,1 vs 2,3)
    const float* __restrict__ W = xhalf ? Wx : Wn;
    const float (* __restrict__ A)[DD] = xhalf ? aX : aN;
    const int c = t & (HH - 1);

    float acc[RT];
#pragma unroll
    for (int r = 0; r < RT; ++r) acc[r] = 0.f;

#pragma unroll 4
    for (int k = 0; k < DD; ++k) {
        float wv = W[k * HH + c];
#pragma unroll
        for (int r = 0; r < RT; ++r) acc[r] += A[r][k] * wv;
    }

    const float bias = xhalf ? bx[c] : bn[c];
#pragma unroll
    for (int r = 0; r < RT; ++r) {
        float v = acc[r] + bias;
        if (RELU) v = fmaxf(v, 0.f);
        out[(long)(r0 + r) * (2 * HH) + t] = v;
    }
}

// ---------------------------------------------------------------------------
// K3: final head: out[1024][64] = f0 @ Wfc + bfc   (f0: [1024][256])
// block = 256 threads = 4 row-groups x 64 cols; 64 rows per block.
// ---------------------------------------------------------------------------
__global__ __launch_bounds__(256)
void head_kernel(const float* __restrict__ f0, const float* __restrict__ Wfc,
                 const float* __restrict__ bfc, float* __restrict__ out) {
    constexpr int RT = 16;
    __shared__ float aX[64][DD];   // 64 KB
    const int r0 = blockIdx.x * 64;
    const int t  = threadIdx.x;

    for (int basei = 0; basei < 64 * DD; basei += 1024) {
        int idx = basei + t * 4;
        int r = idx >> 8, k = idx & 255;
        *(float4*)&aX[r][k] = *(const float4*)(f0 + (long)(r0 + r) * DD + k);
    }
    __syncthreads();

    const int c  = t & (CC - 1);
    const int rg = t >> 6;        // wave-uniform
    float acc[RT];
#pragma unroll
    for (int r = 0; r < RT; ++r) acc[r] = 0.f;

#pragma unroll 4
    for (int k = 0; k < DD; ++k) {
        float wv = Wfc[k * CC + c];
#pragma unroll
        for (int r = 0; r < RT; ++r) acc[r] += aX[rg * RT + r][k] * wv;
    }

    const float bias = bfc[c];
#pragma unroll
    for (int r = 0; r < RT; ++r)
        out[(long)(r0 + rg * RT + r) * CC + c] = acc[r] + bias;
}

// ---------------------------------------------------------------------------
extern "C" void kernel_launch(void* const* d_in, const int* in_sizes, int n_in,
                              void* d_out, int out_size, void* d_ws, size_t ws_size,
                              hipStream_t stream) {
    const int*   ids0 = (const int*)d_in[0];     // [B]
    const int*   ids1 = (const int*)d_in[1];     // [B*S1]
    const int*   ids2 = (const int*)d_in[2];     // [B*S1*S2]
    const float* feat = (const float*)d_in[3];   // [N, D]
    const float* Wx1  = (const float*)d_in[4];
    const float* bx1  = (const float*)d_in[5];
    const float* Wn1  = (const float*)d_in[6];
    const float* bn1  = (const float*)d_in[7];
    const float* Wx2  = (const float*)d_in[8];
    const float* bx2  = (const float*)d_in[9];
    const float* Wn2  = (const float*)d_in[10];
    const float* bn2  = (const float*)d_in[11];
    const float* Wfc  = (const float*)d_in[12];
    const float* bfc  = (const float*)d_in[13];
    float* out = (float*)d_out;                  // [B, C]

    // workspace carve-up (floats)
    float* ws = (float*)d_ws;
    const long M1 = (long)BB * SS1;              // 25600
    float* n1 = ws;                ws += M1 * DD;       // 25600x256
    float* g1 = ws;                ws += M1 * DD;       // 25600x256
    float* n0 = ws;                ws += (long)BB * DD; // 1024x256
    float* g0 = ws;                ws += (long)BB * DD;
    float* gm = ws;                ws += (long)BB * DD;
    float* f0 = ws;                ws += (long)BB * DD;

    // 1) n1[i] = mean over S2 of features[ids2[i*S2+j]]          [25600,256]
    mean_gather<true><<<M1, 64, 0, stream>>>(feat, ids2, n1, SS2, 1.0f / SS2);
    // 2) n0[i] = mean over S1 of features[ids1[i*S1+j]]          [1024,256]
    mean_gather<true><<<BB, 64, 0, stream>>>(feat, ids1, n0, SS1, 1.0f / SS1);
    // 3) g1 = relu([h1.Wx1+bx1 | n1.Wn1+bn1])                    [25600,256]
    agg_layer<true, true><<<M1 / 16, 256, 0, stream>>>(feat, ids1, n1,
                                                       Wx1, bx1, Wn1, bn1, g1);
    // 4) g0 = relu([h0.Wx1+bx1 | n0.Wn1+bn1])                    [1024,256]
    agg_layer<true, true><<<BB / 16, 256, 0, stream>>>(feat, ids0, n0,
                                                       Wx1, bx1, Wn1, bn1, g0);
    // 5) gm[i] = mean over S1 of g1 rows i*S1..i*S1+S1-1         [1024,256]
    mean_gather<false><<<BB, 64, 0, stream>>>(g1, nullptr, gm, SS1, 1.0f / SS1);
    // 6) f0 = [g0.Wx2+bx2 | gm.Wn2+bn2]  (identity act)          [1024,256]
    agg_layer<false, false><<<BB / 16, 256, 0, stream>>>(g0, nullptr, gm,
                                                         Wx2, bx2, Wn2, bn2, f0);
    // 7) out = f0 @ Wfc + bfc                                    [1024,64]
    head_kernel<<<BB / 64, 256, 0, stream>>>(f0, Wfc, bfc, out);
}

// Round 2
// 318.786 us; speedup vs baseline: 1.1518x; 1.1518x over previous
//
#include <hip/hip_runtime.h>

#define DD 256   // in_dim (= 2H)
#define HH 128   // per-branch out dim
#define CC 64    // n_class
#define BB 1024
#define SS1 25
#define SS2 10

typedef __attribute__((ext_vector_type(8))) short bf16x8;
typedef __attribute__((ext_vector_type(4))) float f32x4;

__device__ inline unsigned short f2b(float x) {
    union { float f; unsigned u; } v; v.f = x;
    unsigned r = (v.u + 0x7fffu + ((v.u >> 16) & 1u)) >> 16;
    return (unsigned short)r;
}

// ---------------------------------------------------------------------------
// fp32 row-mean with optional gather (kept for n0 / gm — small)
// ---------------------------------------------------------------------------
template <bool GATHER>
__global__ void mean_gather(const float* __restrict__ src,
                            const int* __restrict__ ids,
                            float* __restrict__ out, int F, float inv) {
    const int row  = blockIdx.x;
    const int lane = threadIdx.x;            // 0..63
    const int base = row * F;
    float4 acc = {0.f, 0.f, 0.f, 0.f};
    for (int j = 0; j < F; ++j) {
        long srow = GATHER ? (long)ids[base + j] : (long)(base + j);
        float4 v = ((const float4*)(src + srow * DD))[lane];
        acc.x += v.x; acc.y += v.y; acc.z += v.z; acc.w += v.w;
    }
    acc.x *= inv; acc.y *= inv; acc.z *= inv; acc.w *= inv;
    ((float4*)(out + (long)row * DD))[lane] = acc;
}

// ---------------------------------------------------------------------------
// n1 producer: out[row][:] = bf16( mean_{j<F} feat[ids[row*F+j]][:] )
// 4 waves/block, one row per wave, F unrolled so all gathers are in flight.
// ---------------------------------------------------------------------------
template <int F>
__global__ __launch_bounds__(256)
void mean_gather_bf(const float* __restrict__ feat, const int* __restrict__ ids,
                    unsigned short* __restrict__ out, float inv) {
    const int row  = blockIdx.x * 4 + (threadIdx.x >> 6);
    const int lane = threadIdx.x & 63;
    const int base = row * F;
    float4 acc = {0.f, 0.f, 0.f, 0.f};
#pragma unroll
    for (int j = 0; j < F; ++j) {
        long r = (long)ids[base + j];
        float4 v = ((const float4*)(feat + r * DD))[lane];
        acc.x += v.x; acc.y += v.y; acc.z += v.z; acc.w += v.w;
    }
    unsigned short o[4] = { f2b(acc.x * inv), f2b(acc.y * inv),
                            f2b(acc.z * inv), f2b(acc.w * inv) };
    *(uint2*)&out[(long)row * DD + lane * 4] = *(uint2*)o;
}

// ---------------------------------------------------------------------------
// W prep: fp32 W[256][128] -> bf16, pre-swizzled into MFMA B-fragment order:
//   Wsw[((kc*8 + nt)*64 + lane)*8 + j] = W[kc*32 + (lane>>4)*8 + j][nt*16 + (lane&15)]
// so each lane's 8 bf16 fragment is one contiguous 16 B load.
// ---------------------------------------------------------------------------
__global__ __launch_bounds__(256)
void prep_w(const float* __restrict__ W, unsigned short* __restrict__ Wsw) {
    const int t    = blockIdx.x * 256 + threadIdx.x;   // 0..4095
    const int lane = t & 63;
    const int frag = t >> 6;                           // kc*8 + nt
    const int kc = frag >> 3, nt = frag & 7;
    const int quad = lane >> 4, lr = lane & 15;
    unsigned short v[8];
#pragma unroll
    for (int j = 0; j < 8; ++j) {
        int k = kc * 32 + quad * 8 + j;
        int n = nt * 16 + lr;
        v[j] = f2b(W[k * HH + n]);
    }
    ((uint4*)Wsw)[t] = *(uint4*)v;
}

// ---------------------------------------------------------------------------
// Half-GEMM via MFMA 16x16x32 bf16:
//   out[m][colOff + n] = act( A[m][:] . W[:][n] + bias[n] ),  n in [0,128)
// MODE 0: A[m] = bf16(feat[ids[m]][:])  (gather+convert during staging)
// MODE 1: A = Asrc (already bf16, row stride DD)
// Block: 256 thr, BM=32 rows. LDS A-tile padded to 264 bf16/row (odd 16B
// stride -> <=2-way bank alias on fragment reads = free). W fragments read
// straight from pre-swizzled global (L2-resident, 16 B/lane coalesced).
// Wave w: row-group rg=w&1 (16 rows), col-tiles nt in [(w>>1)*4, +4).
// ---------------------------------------------------------------------------
template <int MODE, bool RELU>
__global__ __launch_bounds__(256)
void mfma_half(const void* __restrict__ Asrc, const int* __restrict__ ids,
               const unsigned short* __restrict__ Wsw,
               const float* __restrict__ bias,
               float* __restrict__ out, int colOff) {
    constexpr int AS = 264;                    // padded row stride (ushorts)
    __shared__ unsigned short sA[32 * AS];     // 16.9 KB
    __shared__ int sIds[32];
    const int r0 = blockIdx.x * 32;
    const int t  = threadIdx.x;

    if (MODE == 0) {
        if (t < 32) sIds[t] = ids[r0 + t];
        __syncthreads();
#pragma unroll
        for (int i = 0; i < 4; ++i) {          // 32 rows x 32 chunks of 8
            int id = i * 256 + t;
            int row = id >> 5, c = id & 31;
            const float* src = (const float*)Asrc + (long)sIds[row] * DD + c * 8;
            float4 v0 = ((const float4*)src)[0];
            float4 v1 = ((const float4*)src)[1];
            unsigned short w8[8] = { f2b(v0.x), f2b(v0.y), f2b(v0.z), f2b(v0.w),
                                     f2b(v1.x), f2b(v1.y), f2b(v1.z), f2b(v1.w) };
            *(uint4*)&sA[row * AS + c * 8] = *(uint4*)w8;
        }
    } else {
#pragma unroll
        for (int i = 0; i < 4; ++i) {
            int id = i * 256 + t;
            int row = id >> 5, c = id & 31;
            const unsigned short* src =
                (const unsigned short*)Asrc + (long)(r0 + row) * DD + c * 8;
            *(uint4*)&sA[row * AS + c * 8] = *(const uint4*)src;
        }
    }
    __syncthreads();

    const int w = t >> 6, lane = t & 63;
    const int quad = lane >> 4, lr = lane & 15;
    const int rg  = w & 1;
    const int ntb = (w >> 1) * 4;

    f32x4 acc[4] = {};
    const unsigned short* aRow = &sA[(rg * 16 + lr) * AS];
#pragma unroll
    for (int kc = 0; kc < 8; ++kc) {
        bf16x8 a = *(const bf16x8*)&aRow[kc * 32 + quad * 8];
#pragma unroll
        for (int ntl = 0; ntl < 4; ++ntl) {
            bf16x8 b = *(const bf16x8*)&Wsw[(((kc * 8) + ntb + ntl) * 64 + lane) * 8];
            acc[ntl] = __builtin_amdgcn_mfma_f32_16x16x32_bf16(a, b, acc[ntl], 0, 0, 0);
        }
    }

#pragma unroll
    for (int ntl = 0; ntl < 4; ++ntl) {
        int n = (ntb + ntl) * 16 + lr;
        float bv = bias[n];
#pragma unroll
        for (int r = 0; r < 4; ++r) {
            int row = r0 + rg * 16 + quad * 4 + r;   // C/D: row=quad*4+reg, col=lane&15
            float vv = acc[ntl][r] + bv;
            if (RELU) vv = fmaxf(vv, 0.f);
            out[(long)row * DD + colOff + n] = vv;
        }
    }
}

// ---------------------------------------------------------------------------
// fp32 fused aggregator (kept for the small g0 / f0 layers)
// ---------------------------------------------------------------------------
template <bool RELU, bool GATHER>
__global__ __launch_bounds__(256)
void agg_layer(const float* __restrict__ Xsrc, const int* __restrict__ idsX,
               const float* __restrict__ Nbr,
               const float* __restrict__ Wx, const float* __restrict__ bx,
               const float* __restrict__ Wn, const float* __restrict__ bn,
               float* __restrict__ out) {
    constexpr int RT = 16;
    __shared__ float aX[RT][DD];
    __shared__ float aN[RT][DD];
    const int r0 = blockIdx.x * RT;
    const int t  = threadIdx.x;

    for (int basei = 0; basei < RT * DD; basei += 1024) {
        int idx = basei + t * 4;
        int r = idx >> 8, k = idx & 255;
        long row  = r0 + r;
        long xrow = GATHER ? (long)idsX[row] : row;
        *(float4*)&aX[r][k] = *(const float4*)(Xsrc + xrow * DD + k);
        *(float4*)&aN[r][k] = *(const float4*)(Nbr + row * DD + k);
    }
    __syncthreads();

    const bool xhalf = (t < HH);
    const float* __restrict__ W = xhalf ? Wx : Wn;
    const float (* __restrict__ A)[DD] = xhalf ? aX : aN;
    const int c = t & (HH - 1);

    float acc[RT];
#pragma unroll
    for (int r = 0; r < RT; ++r) acc[r] = 0.f;

#pragma unroll 4
    for (int k = 0; k < DD; ++k) {
        float wv = W[k * HH + c];
#pragma unroll
        for (int r = 0; r < RT; ++r) acc[r] += A[r][k] * wv;
    }

    const float bias = xhalf ? bx[c] : bn[c];
#pragma unroll
    for (int r = 0; r < RT; ++r) {
        float v = acc[r] + bias;
        if (RELU) v = fmaxf(v, 0.f);
        out[(long)(r0 + r) * (2 * HH) + t] = v;
    }
}

// ---------------------------------------------------------------------------
// final head: out[1024][64] = f0 @ Wfc + bfc
// ---------------------------------------------------------------------------
__global__ __launch_bounds__(256)
void head_kernel(const float* __restrict__ f0, const float* __restrict__ Wfc,
                 const float* __restrict__ bfc, float* __restrict__ out) {
    constexpr int RT = 16;
    __shared__ float aX[64][DD];
    const int r0 = blockIdx.x * 64;
    const int t  = threadIdx.x;

    for (int basei = 0; basei < 64 * DD; basei += 1024) {
        int idx = basei + t * 4;
        int r = idx >> 8, k = idx & 255;
        *(float4*)&aX[r][k] = *(const float4*)(f0 + (long)(r0 + r) * DD + k);
    }
    __syncthreads();

    const int c  = t & (CC - 1);
    const int rg = t >> 6;
    float acc[RT];
#pragma unroll
    for (int r = 0; r < RT; ++r) acc[r] = 0.f;

#pragma unroll 4
    for (int k = 0; k < DD; ++k) {
        float wv = Wfc[k * CC + c];
#pragma unroll
        for (int r = 0; r < RT; ++r) acc[r] += aX[rg * RT + r][k] * wv;
    }

    const float bias = bfc[c];
#pragma unroll
    for (int r = 0; r < RT; ++r)
        out[(long)(r0 + rg * RT + r) * CC + c] = acc[r] + bias;
}

// ---------------------------------------------------------------------------
extern "C" void kernel_launch(void* const* d_in, const int* in_sizes, int n_in,
                              void* d_out, int out_size, void* d_ws, size_t ws_size,
                              hipStream_t stream) {
    const int*   ids0 = (const int*)d_in[0];
    const int*   ids1 = (const int*)d_in[1];
    const int*   ids2 = (const int*)d_in[2];
    const float* feat = (const float*)d_in[3];
    const float* Wx1  = (const float*)d_in[4];
    const float* bx1  = (const float*)d_in[5];
    const float* Wn1  = (const float*)d_in[6];
    const float* bn1  = (const float*)d_in[7];
    const float* Wx2  = (const float*)d_in[8];
    const float* bx2  = (const float*)d_in[9];
    const float* Wn2  = (const float*)d_in[10];
    const float* bn2  = (const float*)d_in[11];
    const float* Wfc  = (const float*)d_in[12];
    const float* bfc  = (const float*)d_in[13];
    float* out = (float*)d_out;

    const long M1 = (long)BB * SS1;                 // 25600
    float* ws = (float*)d_ws;
    float* g1 = ws;  ws += M1 * DD;                 // 25600x256 fp32
    float* n0 = ws;  ws += (long)BB * DD;
    float* g0 = ws;  ws += (long)BB * DD;
    float* gm = ws;  ws += (long)BB * DD;
    float* f0 = ws;  ws += (long)BB * DD;
    unsigned short* n1b  = (unsigned short*)ws;     // 25600x256 bf16
    unsigned short* WswX = n1b + M1 * DD;           // 32768 bf16
    unsigned short* WswN = WswX + 8 * 8 * 64 * 8;

    // W prep (bf16 + fragment swizzle), 16 blocks each
    prep_w<<<16, 256, 0, stream>>>(Wx1, WswX);
    prep_w<<<16, 256, 0, stream>>>(Wn1, WswN);
    // n1 (bf16): mean over S2 of gathered features      [25600,256]
    mean_gather_bf<SS2><<<M1 / 4, 256, 0, stream>>>(feat, ids2, n1b, 1.0f / SS2);
    // n0 (fp32): mean over S1                           [1024,256]
    mean_gather<true><<<BB, 64, 0, stream>>>(feat, ids1, n0, SS1, 1.0f / SS1);
    // g1 = relu([h1.Wx1 | n1.Wn1]) via MFMA             [25600,256]
    mfma_half<0, true><<<M1 / 32, 256, 0, stream>>>(feat, ids1, WswX, bx1, g1, 0);
    mfma_half<1, true><<<M1 / 32, 256, 0, stream>>>(n1b, nullptr, WswN, bn1, g1, HH);
    // g0 = relu([h0.Wx1 | n0.Wn1])  (fp32, small)       [1024,256]
    agg_layer<true, true><<<BB / 16, 256, 0, stream>>>(feat, ids0, n0,
                                                       Wx1, bx1, Wn1, bn1, g0);
    // gm = mean over S1 of g1 rows                      [1024,256]
    mean_gather<false><<<BB, 64, 0, stream>>>(g1, nullptr, gm, SS1, 1.0f / SS1);
    // f0 = [g0.Wx2 | gm.Wn2]                            [1024,256]
    agg_layer<false, false><<<BB / 16, 256, 0, stream>>>(g0, nullptr, gm,
                                                         Wx2, bx2, Wn2, bn2, f0);
    // out = f0 @ Wfc + bfc                              [1024,64]
    head_kernel<<<BB / 64, 256, 0, stream>>>(f0, Wfc, bfc, out);
}

// Round 3
// 305.480 us; speedup vs baseline: 1.2020x; 1.0436x over previous
//
#include <hip/hip_runtime.h>

#define DD 256   // in_dim (= 2H)
#define HH 128   // per-branch out dim
#define CC 64    // n_class
#define BB 1024
#define SS1 25
#define SS2 10
#define NN 100000

typedef __attribute__((ext_vector_type(8))) short bf16x8;
typedef __attribute__((ext_vector_type(4))) float f32x4;

__device__ inline unsigned short f2b(float x) {
    union { float f; unsigned u; } v; v.f = x;
    unsigned r = (v.u + 0x7fffu + ((v.u >> 16) & 1u)) >> 16;
    return (unsigned short)r;
}
__device__ inline float b2f(unsigned short u) {
    union { unsigned u; float f; } v; v.u = ((unsigned)u) << 16;
    return v.f;
}

// ---------------------------------------------------------------------------
// W prep: [Wx1 | Wn1] fp32 [256][128]x2 -> bf16, MFMA B-fragment order:
//   frag = kc*16 + nt  (kc<8, nt<16; nt<8 -> Wx cols, nt>=8 -> Wn cols)
//   Wsw[(frag*64 + lane)*8 + j] = Wcat[kc*32 + (lane>>4)*8 + j][nt*16 + (lane&15)]
// ---------------------------------------------------------------------------
__global__ __launch_bounds__(256)
void prep_w(const float* __restrict__ Wx, const float* __restrict__ Wn,
            unsigned short* __restrict__ Wsw) {
    const int t    = blockIdx.x * 256 + threadIdx.x;   // 0..8191
    const int lane = t & 63;
    const int frag = t >> 6;                           // kc*16 + nt
    const int kc = frag >> 4, nt = frag & 15;
    const int quad = lane >> 4, lr = lane & 15;
    unsigned short v[8];
#pragma unroll
    for (int j = 0; j < 8; ++j) {
        int k = kc * 32 + quad * 8 + j;
        int n = nt * 16 + lr;                          // 0..255
        float w = (n < HH) ? Wx[k * HH + n] : Wn[k * HH + (n - HH)];
        v[j] = f2b(w);
    }
    ((uint4*)Wsw)[t] = *(uint4*)v;
}

// ---------------------------------------------------------------------------
// PQ = feat @ [Wx1 | Wn1]  -> bf16 [NN][256]   (no bias; added downstream)
// BM=64, block=256 (4 waves). Wave w: rowpair rp=w&1 (32 rows = 2 rowgroups),
// colhalf ch=w>>1 (8 col-tiles). A-tile staged bf16 in LDS (pad stride 264:
// <=2-way bank alias = free). B-fragments streamed from pre-swizzled L2.
// Epilogue transposes acc through LDS for coalesced 16B bf16 stores.
// ---------------------------------------------------------------------------
__global__ __launch_bounds__(256)
void pq_gemm(const float* __restrict__ feat,
             const unsigned short* __restrict__ Wsw,
             unsigned short* __restrict__ PQb) {
    constexpr int AS = 264;    // ushort stride
    constexpr int OS = 260;    // float stride (16B-aligned rows, 2-way banks)
    __shared__ union SM {
        unsigned short a[64 * AS];   // 33.8 KB
        float          o[64 * OS];   // 65.0 KB
    } sm;
    const int r0 = blockIdx.x * 64;
    const int t  = threadIdx.x;

    // stage A: 64 rows x 32 chunks of 8 floats -> bf16
#pragma unroll
    for (int i = 0; i < 8; ++i) {
        int id = i * 256 + t;
        int row = id >> 5, c = id & 31;
        long gr = r0 + row; if (gr > NN - 1) gr = NN - 1;
        const float* src = feat + gr * DD + c * 8;
        float4 v0 = ((const float4*)src)[0];
        float4 v1 = ((const float4*)src)[1];
        unsigned short w8[8] = { f2b(v0.x), f2b(v0.y), f2b(v0.z), f2b(v0.w),
                                 f2b(v1.x), f2b(v1.y), f2b(v1.z), f2b(v1.w) };
        *(uint4*)&sm.a[row * AS + c * 8] = *(uint4*)w8;
    }
    __syncthreads();

    const int w = t >> 6, lane = t & 63;
    const int quad = lane >> 4, lr = lane & 15;
    const int rp = w & 1, ch = w >> 1;

    f32x4 acc[2][8] = {};
#pragma unroll
    for (int kc = 0; kc < 8; ++kc) {
        bf16x8 a0 = *(const bf16x8*)&sm.a[(rp * 32 + lr) * AS + kc * 32 + quad * 8];
        bf16x8 a1 = *(const bf16x8*)&sm.a[(rp * 32 + 16 + lr) * AS + kc * 32 + quad * 8];
#pragma unroll
        for (int ntl = 0; ntl < 8; ++ntl) {
            bf16x8 b = *(const bf16x8*)&Wsw[((kc * 16 + ch * 8 + ntl) * 64 + lane) * 8];
            acc[0][ntl] = __builtin_amdgcn_mfma_f32_16x16x32_bf16(a0, b, acc[0][ntl], 0, 0, 0);
            acc[1][ntl] = __builtin_amdgcn_mfma_f32_16x16x32_bf16(a1, b, acc[1][ntl], 0, 0, 0);
        }
    }
    __syncthreads();   // done reading sm.a

    // acc -> LDS (C layout: row=quad*4+r, col=lr)
#pragma unroll
    for (int rg = 0; rg < 2; ++rg)
#pragma unroll
        for (int ntl = 0; ntl < 8; ++ntl)
#pragma unroll
            for (int r = 0; r < 4; ++r)
                sm.o[(rp * 32 + rg * 16 + quad * 4 + r) * OS + (ch * 8 + ntl) * 16 + lr]
                    = acc[rg][ntl][r];
    __syncthreads();

    // readback, convert, coalesced 16B stores
#pragma unroll
    for (int i = 0; i < 8; ++i) {
        int id = i * 256 + t;
        int row = id >> 5, c = id & 31;
        long gr = r0 + row;
        if (gr < NN) {
            float4 v0 = *(float4*)&sm.o[row * OS + c * 8];
            float4 v1 = *(float4*)&sm.o[row * OS + c * 8 + 4];
            unsigned short w8[8] = { f2b(v0.x), f2b(v0.y), f2b(v0.z), f2b(v0.w),
                                     f2b(v1.x), f2b(v1.y), f2b(v1.z), f2b(v1.w) };
            *(uint4*)&PQb[gr * DD + c * 8] = *(uint4*)w8;
        }
    }
}

// ---------------------------------------------------------------------------
// build_g1: g1b[row] = bf16(relu([PQ[ids1[row]].X + bx1 | mean_j PQ[ids2].N + bn1]))
// one wave per row; 10 neighbor ids distributed via shfl; 4B/lane loads.
// ---------------------------------------------------------------------------
__global__ __launch_bounds__(256)
void build_g1(const unsigned short* __restrict__ PQb,
              const int* __restrict__ ids1, const int* __restrict__ ids2,
              const float* __restrict__ bx1, const float* __restrict__ bn1,
              unsigned short* __restrict__ g1b) {
    const int row  = blockIdx.x * 4 + (threadIdx.x >> 6);
    const int lane = threadIdx.x & 63;

    long xr = (long)ids1[row];
    unsigned xv = *(const unsigned*)&PQb[xr * DD + lane * 2];

    int myid = ids2[row * SS2 + (lane % SS2)];   // lanes 0..9 pattern; shfl below
    float n0 = 0.f, n1 = 0.f;
#pragma unroll
    for (int j = 0; j < SS2; ++j) {
        long nr = (long)__shfl(myid, j);
        unsigned pv = *(const unsigned*)&PQb[nr * DD + HH + lane * 2];
        n0 += b2f((unsigned short)(pv & 0xffff));
        n1 += b2f((unsigned short)(pv >> 16));
    }
    float2 bx = *(const float2*)&bx1[lane * 2];
    float2 bn = *(const float2*)&bn1[lane * 2];
    float x0 = fmaxf(b2f((unsigned short)(xv & 0xffff)) + bx.x, 0.f);
    float x1 = fmaxf(b2f((unsigned short)(xv >> 16)) + bx.y, 0.f);
    n0 = fmaxf(n0 * (1.f / SS2) + bn.x, 0.f);
    n1 = fmaxf(n1 * (1.f / SS2) + bn.y, 0.f);

    unsigned short ox[2] = { f2b(x0), f2b(x1) };
    unsigned short on[2] = { f2b(n0), f2b(n1) };
    *(unsigned*)&g1b[(long)row * DD + lane * 2]      = *(unsigned*)ox;
    *(unsigned*)&g1b[(long)row * DD + HH + lane * 2] = *(unsigned*)on;
}

// ---------------------------------------------------------------------------
// build_g0: g0[row] = relu([PQ[ids0[row]].X + bx1 | mean_{j<25} PQ[ids1].N + bn1])
// fp32 output (feeds fp32 layer-2).
// ---------------------------------------------------------------------------
__global__ __launch_bounds__(256)
void build_g0(const unsigned short* __restrict__ PQb,
              const int* __restrict__ ids0, const int* __restrict__ ids1,
              const float* __restrict__ bx1, const float* __restrict__ bn1,
              float* __restrict__ g0) {
    const int row  = blockIdx.x * 4 + (threadIdx.x >> 6);
    const int lane = threadIdx.x & 63;

    long xr = (long)ids0[row];
    unsigned xv = *(const unsigned*)&PQb[xr * DD + lane * 2];

    int myid = ids1[row * SS1 + (lane % SS1)];
    float n0 = 0.f, n1 = 0.f;
#pragma unroll 5
    for (int j = 0; j < SS1; ++j) {
        long nr = (long)__shfl(myid, j);
        unsigned pv = *(const unsigned*)&PQb[nr * DD + HH + lane * 2];
        n0 += b2f((unsigned short)(pv & 0xffff));
        n1 += b2f((unsigned short)(pv >> 16));
    }
    float2 bx = *(const float2*)&bx1[lane * 2];
    float2 bn = *(const float2*)&bn1[lane * 2];
    float2 xo = { fmaxf(b2f((unsigned short)(xv & 0xffff)) + bx.x, 0.f),
                  fmaxf(b2f((unsigned short)(xv >> 16)) + bx.y, 0.f) };
    float2 no = { fmaxf(n0 * (1.f / SS1) + bn.x, 0.f),
                  fmaxf(n1 * (1.f / SS1) + bn.y, 0.f) };
    *(float2*)&g0[(long)row * DD + lane * 2]      = xo;
    *(float2*)&g0[(long)row * DD + HH + lane * 2] = no;
}

// ---------------------------------------------------------------------------
// agg2 (layer 2, identity act, gm-mean fused):
//   f0[i] = [ g0[i].Wx2 + bx2 | (mean_{j<25} g1b[i*25+j]) . Wn2 + bn2 ]
// ---------------------------------------------------------------------------
__global__ __launch_bounds__(256)
void agg2(const float* __restrict__ g0, const unsigned short* __restrict__ g1b,
          const float* __restrict__ Wx, const float* __restrict__ bx,
          const float* __restrict__ Wn, const float* __restrict__ bn,
          float* __restrict__ f0) {
    constexpr int RT = 16;
    __shared__ float aX[RT][DD];
    __shared__ float aN[RT][DD];
    const int r0 = blockIdx.x * RT;
    const int t  = threadIdx.x;

    // stage: 16 rows x 64 chunks of 4
#pragma unroll
    for (int i = 0; i < 4; ++i) {
        int id = i * 256 + t;
        int r = id >> 6, c4 = (id & 63) * 4;
        *(float4*)&aX[r][c4] = *(const float4*)(g0 + (long)(r0 + r) * DD + c4);
        float4 acc = {0.f, 0.f, 0.f, 0.f};
        const unsigned short* base = g1b + ((long)(r0 + r) * SS1) * DD + c4;
        for (int j = 0; j < SS1; ++j) {
            ushort4 u = *(const ushort4*)(base + (long)j * DD);
            acc.x += b2f(u.x); acc.y += b2f(u.y);
            acc.z += b2f(u.z); acc.w += b2f(u.w);
        }
        acc.x *= (1.f / SS1); acc.y *= (1.f / SS1);
        acc.z *= (1.f / SS1); acc.w *= (1.f / SS1);
        *(float4*)&aN[r][c4] = acc;
    }
    __syncthreads();

    const bool xhalf = (t < HH);
    const float* __restrict__ W = xhalf ? Wx : Wn;
    const float (* __restrict__ A)[DD] = xhalf ? aX : aN;
    const int c = t & (HH - 1);

    float acc[RT];
#pragma unroll
    for (int r = 0; r < RT; ++r) acc[r] = 0.f;
#pragma unroll 4
    for (int k = 0; k < DD; ++k) {
        float wv = W[k * HH + c];
#pragma unroll
        for (int r = 0; r < RT; ++r) acc[r] += A[r][k] * wv;
    }
    const float bias = xhalf ? bx[c] : bn[c];
#pragma unroll
    for (int r = 0; r < RT; ++r)
        f0[(long)(r0 + r) * DD + t] = acc[r] + bias;
}

// ---------------------------------------------------------------------------
// head: out[1024][64] = f0 @ Wfc + bfc
// ---------------------------------------------------------------------------
__global__ __launch_bounds__(256)
void head_kernel(const float* __restrict__ f0, const float* __restrict__ Wfc,
                 const float* __restrict__ bfc, float* __restrict__ out) {
    constexpr int RT = 16;
    __shared__ float aX[64][DD];
    const int r0 = blockIdx.x * 64;
    const int t  = threadIdx.x;

    for (int basei = 0; basei < 64 * DD; basei += 1024) {
        int idx = basei + t * 4;
        int r = idx >> 8, k = idx & 255;
        *(float4*)&aX[r][k] = *(const float4*)(f0 + (long)(r0 + r) * DD + k);
    }
    __syncthreads();

    const int c  = t & (CC - 1);
    const int rg = t >> 6;
    float acc[RT];
#pragma unroll
    for (int r = 0; r < RT; ++r) acc[r] = 0.f;
#pragma unroll 4
    for (int k = 0; k < DD; ++k) {
        float wv = Wfc[k * CC + c];
#pragma unroll
        for (int r = 0; r < RT; ++r) acc[r] += aX[rg * RT + r][k] * wv;
    }
    const float bias = bfc[c];
#pragma unroll
    for (int r = 0; r < RT; ++r)
        out[(long)(r0 + rg * RT + r) * CC + c] = acc[r] + bias;
}

// ---------------------------------------------------------------------------
extern "C" void kernel_launch(void* const* d_in, const int* in_sizes, int n_in,
                              void* d_out, int out_size, void* d_ws, size_t ws_size,
                              hipStream_t stream) {
    const int*   ids0 = (const int*)d_in[0];
    const int*   ids1 = (const int*)d_in[1];
    const int*   ids2 = (const int*)d_in[2];
    const float* feat = (const float*)d_in[3];
    const float* Wx1  = (const float*)d_in[4];
    const float* bx1  = (const float*)d_in[5];
    const float* Wn1  = (const float*)d_in[6];
    const float* bn1  = (const float*)d_in[7];
    const float* Wx2  = (const float*)d_in[8];
    const float* bx2  = (const float*)d_in[9];
    const float* Wn2  = (const float*)d_in[10];
    const float* bn2  = (const float*)d_in[11];
    const float* Wfc  = (const float*)d_in[12];
    const float* bfc  = (const float*)d_in[13];
    float* out = (float*)d_out;

    const long M1 = (long)BB * SS1;                      // 25600
    float* wsf = (float*)d_ws;
    float* g0 = wsf;  wsf += (long)BB * DD;              // 1 MB
    float* f0 = wsf;  wsf += (long)BB * DD;              // 1 MB
    unsigned short* PQb = (unsigned short*)wsf;          // 51.2 MB
    unsigned short* g1b = PQb + (long)NN * DD;           // 13.1 MB
    unsigned short* Wsw = g1b + M1 * DD;                 // 128 KB

    // 1) W prep (bf16 + B-fragment swizzle of [Wx1|Wn1])
    prep_w<<<32, 256, 0, stream>>>(Wx1, Wn1, Wsw);
    // 2) PQ = feat @ [Wx1|Wn1]  (bf16)                  [100000,256]
    pq_gemm<<<(NN + 63) / 64, 256, 0, stream>>>(feat, Wsw, PQb);
    // 3) g1 (bf16)                                      [25600,256]
    build_g1<<<M1 / 4, 256, 0, stream>>>(PQb, ids1, ids2, bx1, bn1, g1b);
    // 4) g0 (fp32)                                      [1024,256]
    build_g0<<<BB / 4, 256, 0, stream>>>(PQb, ids0, ids1, bx1, bn1, g0);
    // 5) f0 = [g0.Wx2 | mean(g1).Wn2] (gm fused)        [1024,256]
    agg2<<<BB / 16, 256, 0, stream>>>(g0, g1b, Wx2, bx2, Wn2, bn2, f0);
    // 6) out = f0 @ Wfc + bfc                           [1024,64]
    head_kernel<<<BB / 64, 256, 0, stream>>>(f0, Wfc, bfc, out);
}